// Round 3
// baseline (812.119 us; speedup 1.0000x reference)
//
#include <hip/hip_runtime.h>

constexpr int D  = 256;
constexpr int K  = 8192;
constexpr int N  = 32768;   // B*S

typedef _Float16 f16;
typedef f16   f16x8  __attribute__((ext_vector_type(8)));
typedef float f32x16 __attribute__((ext_vector_type(16)));

// ============================================================================
// Path A: fp16 3-split + 32x32x16 MFMA.  dot = zh*eh + (zl'*eh + zh*el')/1024
// cbt layout (transposed 16B chunks): chunk s in [0,64), code k:
//   s in [0,32):  eh elements d in [8s, 8s+8)
//   s in [32,64): el' elements d in [8(s-32), 8(s-32)+8)
//   stored at cbt[(s*8192 + k)*8 .. +8)
// ============================================================================

__global__ void esq_kernel(const float* __restrict__ cb, float* __restrict__ esq) {
    const int lane = threadIdx.x & 63;
    const int code = (int)((blockIdx.x * (size_t)blockDim.x + threadIdx.x) >> 6);
    const float4 v = *reinterpret_cast<const float4*>(cb + (size_t)code * D + lane * 4);
    float s = v.x * v.x + v.y * v.y + v.z * v.z + v.w * v.w;
    #pragma unroll
    for (int m = 32; m >= 1; m >>= 1) s += __shfl_xor(s, m);
    if (lane == 0) esq[code] = s;
}

__global__ void cvt_t(const float* __restrict__ cb, f16* __restrict__ cbt) {
    const int g    = blockIdx.x * 256 + threadIdx.x;   // [0, 64*8192)
    const int s    = g >> 13;                          // chunk slot 0..63
    const int code = g & 8191;
    const float* src = cb + (size_t)code * D + (s & 31) * 8;
    const float4 a  = *reinterpret_cast<const float4*>(src);
    const float4 b2 = *reinterpret_cast<const float4*>(src + 4);
    const float vf[8] = {a.x, a.y, a.z, a.w, b2.x, b2.y, b2.z, b2.w};
    f16x8 o;
    if (s < 32) {
        #pragma unroll
        for (int e = 0; e < 8; ++e) o[e] = (f16)vf[e];
    } else {
        #pragma unroll
        for (int e = 0; e < 8; ++e) {
            f16 h = (f16)vf[e];
            o[e] = (f16)((vf[e] - (float)h) * 1024.0f);
        }
    }
    *reinterpret_cast<f16x8*>(cbt + ((size_t)s * 8192 + code) * 8) = o;
}

// Block: 256 threads = 4 waves; wave owns 32 z-rows.
// k-tile = 64 codes; LDS double buffer 2 x 64 KB, one barrier per k-tile.
__launch_bounds__(256, 1)
__global__ void vq32(const float* __restrict__ z, const f16* __restrict__ cbt,
                     const float* __restrict__ esq, const float* __restrict__ cb,
                     float* __restrict__ out) {
    __shared__ f16 buf[2][32768];   // [chunk s 0..63][code 0..63][8 f16]

    const int tid  = threadIdx.x;
    const int w    = tid >> 6;
    const int l    = tid & 63;
    const int cid  = l & 31;
    const int half = l >> 5;
    const size_t wrow0 = (size_t)blockIdx.x * 128 + w * 32;

    // ---- A fragments in registers: 32 rows, 16 d-chunks of K=16 ----
    // lane l holds A[row = l&31][k = u*16 + (l>>5)*8 + e]
    f16x8 zh[16], zl[16];
    {
        const float* zr = z + (wrow0 + cid) * D + half * 8;
        #pragma unroll
        for (int u = 0; u < 16; ++u) {
            float4 a  = *reinterpret_cast<const float4*>(zr + u * 16);
            float4 b2 = *reinterpret_cast<const float4*>(zr + u * 16 + 4);
            float vf[8] = {a.x, a.y, a.z, a.w, b2.x, b2.y, b2.z, b2.w};
            f16x8 h, lo;
            #pragma unroll
            for (int e = 0; e < 8; ++e) {
                f16 hh = (f16)vf[e];
                h[e]  = hh;
                lo[e] = (f16)((vf[e] - (float)hh) * 1024.0f);
            }
            zh[u] = h; zl[u] = lo;
        }
    }

    float minv[16];
    int   mini[16];
    #pragma unroll
    for (int g = 0; g < 16; ++g) { minv[g] = 3.0e38f; mini[g] = 0; }

    f32x16 accA0 = (f32x16)0.0f, accA1 = (f32x16)0.0f;
    f32x16 accB0 = (f32x16)0.0f, accB1 = (f32x16)0.0f;

    // ---- prologue: stage k-tile 0 into buf[0] ----
    int4 st[16];
    #pragma unroll
    for (int i = 0; i < 16; ++i)
        st[i] = *reinterpret_cast<const int4*>(cbt + ((size_t)(i * 4 + w) * 8192 + l) * 8);
    #pragma unroll
    for (int i = 0; i < 16; ++i)
        *reinterpret_cast<int4*>(&buf[0][((i * 4 + w) * 64 + l) * 8]) = st[i];
    __syncthreads();

    for (int kt = 0; kt < 128; ++kt) {
        const int  b        = kt & 1;
        const bool haveNext = (kt < 127);

        // issue next tile's global loads early (in flight across compute)
        if (haveNext) {
            const int k0n = (kt + 1) * 64;
            #pragma unroll
            for (int i = 0; i < 16; ++i)
                st[i] = *reinterpret_cast<const int4*>(
                    cbt + ((size_t)(i * 4 + w) * 8192 + k0n + l) * 8);
        }
        const float es0 = esq[kt * 64 + cid];
        const float es1 = esq[kt * 64 + 32 + cid];

        // ---- compute: 64 ds_read_b128 + 96 MFMA ----
        const f16* Bp = &buf[b][0];
        #pragma unroll
        for (int u = 0; u < 16; ++u) {
            f16x8 beh0 = *reinterpret_cast<const f16x8*>(Bp + ((2 * u + half) * 64 + cid) * 8);
            f16x8 beh1 = *reinterpret_cast<const f16x8*>(Bp + ((2 * u + half) * 64 + 32 + cid) * 8);
            f16x8 bel0 = *reinterpret_cast<const f16x8*>(Bp + ((32 + 2 * u + half) * 64 + cid) * 8);
            f16x8 bel1 = *reinterpret_cast<const f16x8*>(Bp + ((32 + 2 * u + half) * 64 + 32 + cid) * 8);
            accA0 = __builtin_amdgcn_mfma_f32_32x32x16_f16(zh[u], beh0, accA0, 0, 0, 0);
            accA1 = __builtin_amdgcn_mfma_f32_32x32x16_f16(zh[u], beh1, accA1, 0, 0, 0);
            accB0 = __builtin_amdgcn_mfma_f32_32x32x16_f16(zl[u], beh0, accB0, 0, 0, 0);
            accB1 = __builtin_amdgcn_mfma_f32_32x32x16_f16(zl[u], beh1, accB1, 0, 0, 0);
            accB0 = __builtin_amdgcn_mfma_f32_32x32x16_f16(zh[u], bel0, accB0, 0, 0, 0);
            accB1 = __builtin_amdgcn_mfma_f32_32x32x16_f16(zh[u], bel1, accB1, 0, 0, 0);
        }

        // write next tile late (T14), one barrier per k-tile
        if (haveNext) {
            f16* Wp = &buf[b ^ 1][0];
            #pragma unroll
            for (int i = 0; i < 16; ++i)
                *reinterpret_cast<int4*>(Wp + ((i * 4 + w) * 64 + l) * 8) = st[i];
        }
        __syncthreads();

        // ---- epilogue: scores + running argmin (regs only) ----
        // C/D: col(code) = l&31, row = (g&3) + 8*(g>>2) + 4*(l>>5)
        const int c0 = kt * 64 + cid;
        const int c1 = c0 + 32;
        #pragma unroll
        for (int g = 0; g < 16; ++g) {
            float d0 = fmaf(accB0[g], 0.0009765625f, accA0[g]);
            float s0 = fmaf(-2.0f, d0, es0);
            if (s0 < minv[g]) { minv[g] = s0; mini[g] = c0; }
            float d1 = fmaf(accB1[g], 0.0009765625f, accA1[g]);
            float s1 = fmaf(-2.0f, d1, es1);
            if (s1 < minv[g]) { minv[g] = s1; mini[g] = c1; }
        }
        accA0 = (f32x16)0.0f; accA1 = (f32x16)0.0f;
        accB0 = (f32x16)0.0f; accB1 = (f32x16)0.0f;
    }

    // ---- final: merge across 32 lanes per half (tie -> lower), gather ----
    float* out_idx = out + (size_t)N * D;
    #pragma unroll
    for (int g = 0; g < 16; ++g) {
        float v   = minv[g];
        int   idx = mini[g];
        #pragma unroll
        for (int m = 1; m < 32; m <<= 1) {
            float ov = __shfl_xor(v, m);
            int   oi = __shfl_xor(idx, m);
            if (ov < v || (ov == v && oi < idx)) { v = ov; idx = oi; }
        }
        const size_t row = wrow0 + (g & 3) + 8 * (g >> 2) + 4 * half;
        if (cid == 0) out_idx[row] = (float)idx;
        const float4* src = reinterpret_cast<const float4*>(cb + (size_t)idx * D);
        float4*       dst = reinterpret_cast<float4*>(out + row * D);
        dst[cid]      = src[cid];
        dst[cid + 32] = src[cid + 32];
    }
}

// ============================================================================
// Path B (fallback if ws too small): round-1 fp32 kernels (verified exact).
// ============================================================================
constexpr int BM = 128, BN = 128, TD = 32, ZS = 260, CS = 36;

__launch_bounds__(256)
__global__ void vq_kernel(const float* __restrict__ z, const float* __restrict__ cb,
                          const float* __restrict__ esq, float* __restrict__ out) {
    __shared__ float zs[BM * ZS];
    __shared__ float cs[BN * CS];
    const int tid = threadIdx.x;
    const int tx  = tid & 15;
    const int ty  = tid >> 4;
    const size_t row0 = (size_t)blockIdx.x * BM;
    #pragma unroll
    for (int i = 0; i < 32; ++i) {
        int f  = tid + i * 256;
        int r  = f >> 6;
        int c4 = (f & 63) * 4;
        *reinterpret_cast<float4*>(&zs[r * ZS + c4]) =
            *reinterpret_cast<const float4*>(z + (row0 + r) * D + c4);
    }
    float minv[8]; int mini[8];
    #pragma unroll
    for (int i = 0; i < 8; ++i) { minv[i] = 3.4e38f; mini[i] = 0; }
    for (int k0 = 0; k0 < K; k0 += BN) {
        float acc[8][8];
        #pragma unroll
        for (int i = 0; i < 8; ++i)
            #pragma unroll
            for (int j = 0; j < 8; ++j) acc[i][j] = 0.0f;
        for (int dc = 0; dc < D; dc += TD) {
            __syncthreads();
            int c = tid >> 3, c4 = (tid & 7) * 4;
            #pragma unroll
            for (int i = 0; i < 4; ++i)
                *reinterpret_cast<float4*>(&cs[(c + 32 * i) * CS + c4]) =
                    *reinterpret_cast<const float4*>(cb + (size_t)(k0 + c + 32 * i) * D + dc + c4);
            __syncthreads();
            for (int d4 = 0; d4 < TD; d4 += 4) {
                float4 a[8], b[8];
                #pragma unroll
                for (int i = 0; i < 8; ++i)
                    a[i] = *reinterpret_cast<const float4*>(&zs[(ty + 16 * i) * ZS + dc + d4]);
                #pragma unroll
                for (int j = 0; j < 8; ++j)
                    b[j] = *reinterpret_cast<const float4*>(&cs[(tx + 16 * j) * CS + d4]);
                #pragma unroll
                for (int i = 0; i < 8; ++i)
                    #pragma unroll
                    for (int j = 0; j < 8; ++j)
                        acc[i][j] += a[i].x * b[j].x + a[i].y * b[j].y
                                   + a[i].z * b[j].z + a[i].w * b[j].w;
            }
        }
        #pragma unroll
        for (int j = 0; j < 8; ++j) {
            int code = k0 + tx + 16 * j;
            float es = esq[code];
            #pragma unroll
            for (int i = 0; i < 8; ++i) {
                float score = fmaf(-2.0f, acc[i][j], es);
                if (score < minv[i]) { minv[i] = score; mini[i] = code; }
            }
        }
    }
    float* out_idx = out + (size_t)N * D;
    #pragma unroll
    for (int i = 0; i < 8; ++i) {
        float v = minv[i]; int idx = mini[i];
        #pragma unroll
        for (int m = 1; m < 16; m <<= 1) {
            float ov = __shfl_xor(v, m);
            int   oi = __shfl_xor(idx, m);
            if (ov < v || (ov == v && oi < idx)) { v = ov; idx = oi; }
        }
        size_t row = row0 + ty + 16 * i;
        if (tx == 0) out_idx[row] = (float)idx;
        const float4* src = reinterpret_cast<const float4*>(cb + (size_t)idx * D);
        float4*       dst = reinterpret_cast<float4*>(out + row * D);
        #pragma unroll
        for (int t = 0; t < 4; ++t) dst[tx + 16 * t] = src[tx + 16 * t];
    }
}

extern "C" void kernel_launch(void* const* d_in, const int* in_sizes, int n_in,
                              void* d_out, int out_size, void* d_ws, size_t ws_size,
                              hipStream_t stream) {
    const float* z   = (const float*)d_in[0];
    const float* cb  = (const float*)d_in[1];
    float*       out = (float*)d_out;

    const size_t cbt_bytes = (size_t)K * 512 * sizeof(f16);   // 8 MB
    const size_t need = cbt_bytes + (size_t)K * sizeof(float);

    if (ws_size >= need) {
        f16*   cbt  = (f16*)d_ws;
        float* esqp = (float*)((char*)d_ws + cbt_bytes);
        esq_kernel<<<(K * 64) / 256, 256, 0, stream>>>(cb, esqp);
        cvt_t<<<(K * 64) / 256, 256, 0, stream>>>(cb, cbt);
        vq32<<<N / 128, 256, 0, stream>>>(z, cbt, esqp, cb, out);
    } else {
        float* esqp = (float*)d_ws;
        esq_kernel<<<(K * 64) / 256, 256, 0, stream>>>(cb, esqp);
        vq_kernel<<<N / BM, 256, 0, stream>>>(z, cb, esqp, out);
    }
}

// Round 4
// 412.997 us; speedup vs baseline: 1.9664x; 1.9664x over previous
//
#include <hip/hip_runtime.h>

constexpr int D  = 256;
constexpr int K  = 8192;
constexpr int N  = 32768;   // B*S

typedef _Float16 f16;
typedef f16   f16x8  __attribute__((ext_vector_type(8)));
typedef float f32x16 __attribute__((ext_vector_type(16)));

__device__ __forceinline__ void gload_lds16(const void* g, void* l) {
    __builtin_amdgcn_global_load_lds(
        (const __attribute__((address_space(1))) unsigned int*)g,
        (__attribute__((address_space(3))) unsigned int*)l,
        16, 0, 0);
}

// ============================================================================
// Path A: fp16 3-split + 32x32x16 MFMA.  dot = zh*eh + (zl'*eh + zh*el')/1024
// cbt layout (transposed 16B chunks): chunk s in [0,64), code k:
//   s in [0,32):  eh elements d in [8s, 8s+8)
//   s in [32,64): el' elements d in [8(s-32), 8(s-32)+8)
//   stored at cbt[(s*8192 + k)*8 .. +8)
// ============================================================================

__global__ void esq_kernel(const float* __restrict__ cb, float* __restrict__ esq) {
    const int lane = threadIdx.x & 63;
    const int code = (int)((blockIdx.x * (size_t)blockDim.x + threadIdx.x) >> 6);
    const float4 v = *reinterpret_cast<const float4*>(cb + (size_t)code * D + lane * 4);
    float s = v.x * v.x + v.y * v.y + v.z * v.z + v.w * v.w;
    #pragma unroll
    for (int m = 32; m >= 1; m >>= 1) s += __shfl_xor(s, m);
    if (lane == 0) esq[code] = s;
}

__global__ void cvt_t(const float* __restrict__ cb, f16* __restrict__ cbt) {
    const int g    = blockIdx.x * 256 + threadIdx.x;   // [0, 64*8192)
    const int s    = g >> 13;                          // chunk slot 0..63
    const int code = g & 8191;
    const float* src = cb + (size_t)code * D + (s & 31) * 8;
    const float4 a  = *reinterpret_cast<const float4*>(src);
    const float4 b2 = *reinterpret_cast<const float4*>(src + 4);
    const float vf[8] = {a.x, a.y, a.z, a.w, b2.x, b2.y, b2.z, b2.w};
    f16x8 o;
    if (s < 32) {
        #pragma unroll
        for (int e = 0; e < 8; ++e) o[e] = (f16)vf[e];
    } else {
        #pragma unroll
        for (int e = 0; e < 8; ++e) {
            f16 h = (f16)vf[e];
            o[e] = (f16)((vf[e] - (float)h) * 1024.0f);
        }
    }
    *reinterpret_cast<f16x8*>(cbt + ((size_t)s * 8192 + code) * 8) = o;
}

// Block: 256 threads = 4 waves; wave owns 32 z-rows.
// k-tile = 64 codes; LDS double buffer 2 x 64 KB; global_load_lds staging
// (zero staging VGPRs); one barrier per k-tile.
__launch_bounds__(256, 1)
__global__ void vq32(const float* __restrict__ z, const f16* __restrict__ cbt,
                     const float* __restrict__ esq, const float* __restrict__ cb,
                     float* __restrict__ out) {
    __shared__ f16 buf[2][32768];   // [chunk s 0..63][code 0..63][8 f16]

    const int tid  = threadIdx.x;
    const int w    = tid >> 6;
    const int l    = tid & 63;
    const int cid  = l & 31;
    const int half = l >> 5;
    const size_t wrow0 = (size_t)blockIdx.x * 128 + w * 32;

    // ---- A fragments in registers: 32 rows, 16 d-chunks of K=16 ----
    // lane l holds A[row = l&31][k = u*16 + (l>>5)*8 + e]
    f16x8 zh[16], zl[16];
    {
        const float* zr = z + (wrow0 + cid) * D + half * 8;
        #pragma unroll
        for (int u = 0; u < 16; ++u) {
            float4 a  = *reinterpret_cast<const float4*>(zr + u * 16);
            float4 b2 = *reinterpret_cast<const float4*>(zr + u * 16 + 4);
            float vf[8] = {a.x, a.y, a.z, a.w, b2.x, b2.y, b2.z, b2.w};
            f16x8 h, lo;
            #pragma unroll
            for (int e = 0; e < 8; ++e) {
                f16 hh = (f16)vf[e];
                h[e]  = hh;
                lo[e] = (f16)((vf[e] - (float)hh) * 1024.0f);
            }
            zh[u] = h; zl[u] = lo;
        }
    }

    float minv[16];
    int   mini[16];
    #pragma unroll
    for (int g = 0; g < 16; ++g) { minv[g] = 3.0e38f; mini[g] = 0; }

    f32x16 accA0 = (f32x16)0.0f, accA1 = (f32x16)0.0f;
    f32x16 accB0 = (f32x16)0.0f, accB1 = (f32x16)0.0f;

    // ---- staging: wave w DMAs chunk slices s = w*16 .. w*16+15 ----
    // lane l -> code (k0 + l); LDS dest wave-uniform, HW writes lane*16B.
    // ---- prologue: stage k-tile 0 into buf[0] ----
    {
        #pragma unroll
        for (int i = 0; i < 16; ++i) {
            const int s = w * 16 + i;
            gload_lds16(cbt + ((size_t)s * 8192 + l) * 8, &buf[0][(s * 64) * 8]);
        }
    }
    __syncthreads();

    for (int kt = 0; kt < 128; ++kt) {
        const int  b        = kt & 1;
        const bool haveNext = (kt < 127);

        // issue next tile's DMA early (in flight across this tile's compute)
        if (haveNext) {
            const int k0n = (kt + 1) * 64;
            #pragma unroll
            for (int i = 0; i < 16; ++i) {
                const int s = w * 16 + i;
                gload_lds16(cbt + ((size_t)s * 8192 + k0n + l) * 8,
                            &buf[b ^ 1][(s * 64) * 8]);
            }
        }
        const float es0 = esq[kt * 64 + cid];
        const float es1 = esq[kt * 64 + 32 + cid];

        // ---- compute: 64 ds_read_b128 + 96 MFMA per wave ----
        const f16* Bp = &buf[b][0];
        #pragma unroll
        for (int u = 0; u < 16; ++u) {
            f16x8 beh0 = *reinterpret_cast<const f16x8*>(Bp + ((2 * u + half) * 64 + cid) * 8);
            f16x8 beh1 = *reinterpret_cast<const f16x8*>(Bp + ((2 * u + half) * 64 + 32 + cid) * 8);
            f16x8 bel0 = *reinterpret_cast<const f16x8*>(Bp + ((32 + 2 * u + half) * 64 + cid) * 8);
            f16x8 bel1 = *reinterpret_cast<const f16x8*>(Bp + ((32 + 2 * u + half) * 64 + 32 + cid) * 8);
            accA0 = __builtin_amdgcn_mfma_f32_32x32x16_f16(zh[u], beh0, accA0, 0, 0, 0);
            accA1 = __builtin_amdgcn_mfma_f32_32x32x16_f16(zh[u], beh1, accA1, 0, 0, 0);
            accB0 = __builtin_amdgcn_mfma_f32_32x32x16_f16(zl[u], beh0, accB0, 0, 0, 0);
            accB1 = __builtin_amdgcn_mfma_f32_32x32x16_f16(zl[u], beh1, accB1, 0, 0, 0);
            accB0 = __builtin_amdgcn_mfma_f32_32x32x16_f16(zh[u], bel0, accB0, 0, 0, 0);
            accB1 = __builtin_amdgcn_mfma_f32_32x32x16_f16(zh[u], bel1, accB1, 0, 0, 0);
        }

        // ---- epilogue: scores + running argmin (regs only) ----
        // C/D: col(code) = l&31, row = (g&3) + 8*(g>>2) + 4*(l>>5)
        const int c0 = kt * 64 + cid;
        const int c1 = c0 + 32;
        #pragma unroll
        for (int g = 0; g < 16; ++g) {
            float d0 = fmaf(accB0[g], 0.0009765625f, accA0[g]);
            float s0 = fmaf(-2.0f, d0, es0);
            if (s0 < minv[g]) { minv[g] = s0; mini[g] = c0; }
            float d1 = fmaf(accB1[g], 0.0009765625f, accA1[g]);
            float s1 = fmaf(-2.0f, d1, es1);
            if (s1 < minv[g]) { minv[g] = s1; mini[g] = c1; }
        }
        accA0 = (f32x16)0.0f; accA1 = (f32x16)0.0f;
        accB0 = (f32x16)0.0f; accB1 = (f32x16)0.0f;

        // barrier drains the DMA (vmcnt) -> buf[b^1] ready for next iter
        if (haveNext) __syncthreads();
    }

    // ---- final: merge across 32 lanes per half (tie -> lower), gather ----
    float* out_idx = out + (size_t)N * D;
    #pragma unroll
    for (int g = 0; g < 16; ++g) {
        float v   = minv[g];
        int   idx = mini[g];
        #pragma unroll
        for (int m = 1; m < 32; m <<= 1) {
            float ov = __shfl_xor(v, m);
            int   oi = __shfl_xor(idx, m);
            if (ov < v || (ov == v && oi < idx)) { v = ov; idx = oi; }
        }
        const size_t row = wrow0 + (g & 3) + 8 * (g >> 2) + 4 * half;
        if (cid == 0) out_idx[row] = (float)idx;
        const float4* src = reinterpret_cast<const float4*>(cb + (size_t)idx * D);
        float4*       dst = reinterpret_cast<float4*>(out + row * D);
        dst[cid]      = src[cid];
        dst[cid + 32] = src[cid + 32];
    }
}

// ============================================================================
// Path B (fallback if ws too small): round-1 fp32 kernels (verified exact).
// ============================================================================
constexpr int BM = 128, BN = 128, TD = 32, ZS = 260, CS = 36;

__launch_bounds__(256)
__global__ void vq_kernel(const float* __restrict__ z, const float* __restrict__ cb,
                          const float* __restrict__ esq, float* __restrict__ out) {
    __shared__ float zs[BM * ZS];
    __shared__ float cs[BN * CS];
    const int tid = threadIdx.x;
    const int tx  = tid & 15;
    const int ty  = tid >> 4;
    const size_t row0 = (size_t)blockIdx.x * BM;
    #pragma unroll
    for (int i = 0; i < 32; ++i) {
        int f  = tid + i * 256;
        int r  = f >> 6;
        int c4 = (f & 63) * 4;
        *reinterpret_cast<float4*>(&zs[r * ZS + c4]) =
            *reinterpret_cast<const float4*>(z + (row0 + r) * D + c4);
    }
    float minv[8]; int mini[8];
    #pragma unroll
    for (int i = 0; i < 8; ++i) { minv[i] = 3.4e38f; mini[i] = 0; }
    for (int k0 = 0; k0 < K; k0 += BN) {
        float acc[8][8];
        #pragma unroll
        for (int i = 0; i < 8; ++i)
            #pragma unroll
            for (int j = 0; j < 8; ++j) acc[i][j] = 0.0f;
        for (int dc = 0; dc < D; dc += TD) {
            __syncthreads();
            int c = tid >> 3, c4 = (tid & 7) * 4;
            #pragma unroll
            for (int i = 0; i < 4; ++i)
                *reinterpret_cast<float4*>(&cs[(c + 32 * i) * CS + c4]) =
                    *reinterpret_cast<const float4*>(cb + (size_t)(k0 + c + 32 * i) * D + dc + c4);
            __syncthreads();
            for (int d4 = 0; d4 < TD; d4 += 4) {
                float4 a[8], b[8];
                #pragma unroll
                for (int i = 0; i < 8; ++i)
                    a[i] = *reinterpret_cast<const float4*>(&zs[(ty + 16 * i) * ZS + dc + d4]);
                #pragma unroll
                for (int j = 0; j < 8; ++j)
                    b[j] = *reinterpret_cast<const float4*>(&cs[(tx + 16 * j) * CS + d4]);
                #pragma unroll
                for (int i = 0; i < 8; ++i)
                    #pragma unroll
                    for (int j = 0; j < 8; ++j)
                        acc[i][j] += a[i].x * b[j].x + a[i].y * b[j].y
                                   + a[i].z * b[j].z + a[i].w * b[j].w;
            }
        }
        #pragma unroll
        for (int j = 0; j < 8; ++j) {
            int code = k0 + tx + 16 * j;
            float es = esq[code];
            #pragma unroll
            for (int i = 0; i < 8; ++i) {
                float score = fmaf(-2.0f, acc[i][j], es);
                if (score < minv[i]) { minv[i] = score; mini[i] = code; }
            }
        }
    }
    float* out_idx = out + (size_t)N * D;
    #pragma unroll
    for (int i = 0; i < 8; ++i) {
        float v = minv[i]; int idx = mini[i];
        #pragma unroll
        for (int m = 1; m < 16; m <<= 1) {
            float ov = __shfl_xor(v, m);
            int   oi = __shfl_xor(idx, m);
            if (ov < v || (ov == v && oi < idx)) { v = ov; idx = oi; }
        }
        size_t row = row0 + ty + 16 * i;
        if (tx == 0) out_idx[row] = (float)idx;
        const float4* src = reinterpret_cast<const float4*>(cb + (size_t)idx * D);
        float4*       dst = reinterpret_cast<float4*>(out + row * D);
        #pragma unroll
        for (int t = 0; t < 4; ++t) dst[tx + 16 * t] = src[tx + 16 * t];
    }
}

extern "C" void kernel_launch(void* const* d_in, const int* in_sizes, int n_in,
                              void* d_out, int out_size, void* d_ws, size_t ws_size,
                              hipStream_t stream) {
    const float* z   = (const float*)d_in[0];
    const float* cb  = (const float*)d_in[1];
    float*       out = (float*)d_out;

    const size_t cbt_bytes = (size_t)K * 512 * sizeof(f16);   // 8 MB
    const size_t need = cbt_bytes + (size_t)K * sizeof(float);

    if (ws_size >= need) {
        f16*   cbt  = (f16*)d_ws;
        float* esqp = (float*)((char*)d_ws + cbt_bytes);
        esq_kernel<<<(K * 64) / 256, 256, 0, stream>>>(cb, esqp);
        cvt_t<<<(K * 64) / 256, 256, 0, stream>>>(cb, cbt);
        vq32<<<N / 128, 256, 0, stream>>>(z, cbt, esqp, cb, out);
    } else {
        float* esqp = (float*)d_ws;
        esq_kernel<<<(K * 64) / 256, 256, 0, stream>>>(cb, esqp);
        vq_kernel<<<N / BM, 256, 0, stream>>>(z, cb, esqp, out);
    }
}

// Round 5
// 368.913 us; speedup vs baseline: 2.2014x; 1.1195x over previous
//
#include <hip/hip_runtime.h>

constexpr int D  = 256;
constexpr int K  = 8192;
constexpr int N  = 32768;   // B*S

typedef _Float16 f16;
typedef f16   f16x8  __attribute__((ext_vector_type(8)));
typedef float f32x16 __attribute__((ext_vector_type(16)));

__device__ __forceinline__ void gload_lds16(const void* g, void* l) {
    __builtin_amdgcn_global_load_lds(
        (const __attribute__((address_space(1))) unsigned int*)g,
        (__attribute__((address_space(3))) unsigned int*)l,
        16, 0, 0);
}

// ============================================================================
// Path A: fp16 3-split + 32x32x16 MFMA.  dot = zh*eh + (zl'*eh + zh*el')/1024
// cbt layout (transposed 16B chunks): chunk s in [0,64), code k:
//   s in [0,32):  eh elements d in [8s, 8s+8)
//   s in [32,64): el' elements d in [8(s-32), 8(s-32)+8)
//   stored at cbt[(s*8192 + k)*8 .. +8)
// Grid 512 = 256 row-groups x 2 K-halves; block = 4 waves x 32 rows,
// scans 4096 codes in 128 k-tiles of 32; LDS 2x32KB -> 2 blocks/CU.
// ============================================================================

__global__ void esq_kernel(const float* __restrict__ cb, float* __restrict__ esq) {
    const int lane = threadIdx.x & 63;
    const int code = (int)((blockIdx.x * (size_t)blockDim.x + threadIdx.x) >> 6);
    const float4 v = *reinterpret_cast<const float4*>(cb + (size_t)code * D + lane * 4);
    float s = v.x * v.x + v.y * v.y + v.z * v.z + v.w * v.w;
    #pragma unroll
    for (int m = 32; m >= 1; m >>= 1) s += __shfl_xor(s, m);
    if (lane == 0) esq[code] = s;
}

__global__ void cvt_t(const float* __restrict__ cb, f16* __restrict__ cbt) {
    const int g    = blockIdx.x * 256 + threadIdx.x;   // [0, 64*8192)
    const int s    = g >> 13;                          // chunk slot 0..63
    const int code = g & 8191;
    const float* src = cb + (size_t)code * D + (s & 31) * 8;
    const float4 a  = *reinterpret_cast<const float4*>(src);
    const float4 b2 = *reinterpret_cast<const float4*>(src + 4);
    const float vf[8] = {a.x, a.y, a.z, a.w, b2.x, b2.y, b2.z, b2.w};
    f16x8 o;
    if (s < 32) {
        #pragma unroll
        for (int e = 0; e < 8; ++e) o[e] = (f16)vf[e];
    } else {
        #pragma unroll
        for (int e = 0; e < 8; ++e) {
            f16 h = (f16)vf[e];
            o[e] = (f16)((vf[e] - (float)h) * 1024.0f);
        }
    }
    *reinterpret_cast<f16x8*>(cbt + ((size_t)s * 8192 + code) * 8) = o;
}

__launch_bounds__(256, 2)
__global__ void vq32(const float* __restrict__ z, const f16* __restrict__ cbt,
                     const float* __restrict__ esq,
                     float* __restrict__ wsv, int* __restrict__ wsi) {
    __shared__ f16 buf[2][16384];   // [64 slots][32 codes][8 f16] = 32 KB each

    const int tid  = threadIdx.x;
    const int w    = tid >> 6;
    const int l    = tid & 63;
    const int cid  = l & 31;
    const int half = l >> 5;
    const int rg    = blockIdx.x >> 1;
    const int kh    = blockIdx.x & 1;
    const int kbase = kh * 4096;
    const size_t wrow0 = (size_t)rg * 128 + w * 32;

    // ---- A fragments in registers: 32 rows, 16 d-chunks of K=16 ----
    // lane l holds A[row = l&31][k = u*16 + (l>>5)*8 + e]
    f16x8 zh[16], zl[16];
    {
        const float* zr = z + (wrow0 + cid) * D + half * 8;
        #pragma unroll
        for (int u = 0; u < 16; ++u) {
            float4 a  = *reinterpret_cast<const float4*>(zr + u * 16);
            float4 b2 = *reinterpret_cast<const float4*>(zr + u * 16 + 4);
            float vf[8] = {a.x, a.y, a.z, a.w, b2.x, b2.y, b2.z, b2.w};
            f16x8 h, lo;
            #pragma unroll
            for (int e = 0; e < 8; ++e) {
                f16 hh = (f16)vf[e];
                h[e]  = hh;
                lo[e] = (f16)((vf[e] - (float)hh) * 1024.0f);
            }
            zh[u] = h; zl[u] = lo;
        }
    }

    float minv[16];
    int   mini[16];
    #pragma unroll
    for (int g = 0; g < 16; ++g) { minv[g] = 3.0e38f; mini[g] = 0; }

    f32x16 accA = (f32x16)0.0f, accB = (f32x16)0.0f;

    // ---- staging: wave w DMAs slots [w*16, w*16+16); instr j covers 2 slots.
    // lane l -> slot (base+2j+(l>>5)), code (k0 + (l&31)); dest linear 1 KB.
    #pragma unroll
    for (int j = 0; j < 8; ++j) {
        const int s = w * 16 + 2 * j + half;
        gload_lds16(cbt + ((size_t)s * 8192 + kbase + cid) * 8,
                    &buf[0][(w * 16 + 2 * j) * 256]);
    }
    __syncthreads();

    for (int kt = 0; kt < 128; ++kt) {
        const int  b        = kt & 1;
        const bool haveNext = (kt < 127);

        if (haveNext) {
            const int k0n = kbase + (kt + 1) * 32;
            #pragma unroll
            for (int j = 0; j < 8; ++j) {
                const int s = w * 16 + 2 * j + half;
                gload_lds16(cbt + ((size_t)s * 8192 + k0n + cid) * 8,
                            &buf[b ^ 1][(w * 16 + 2 * j) * 256]);
            }
        }
        const float es = esq[kbase + kt * 32 + cid];

        // ---- compute: 32 ds_read_b128 + 48 MFMA per wave ----
        const f16* Bp = &buf[b][0];
        __builtin_amdgcn_s_setprio(1);
        #pragma unroll
        for (int u = 0; u < 16; ++u) {
            f16x8 beh = *reinterpret_cast<const f16x8*>(Bp + ((2 * u + half) * 32 + cid) * 8);
            f16x8 bel = *reinterpret_cast<const f16x8*>(Bp + ((32 + 2 * u + half) * 32 + cid) * 8);
            accA = __builtin_amdgcn_mfma_f32_32x32x16_f16(zh[u], beh, accA, 0, 0, 0);
            accB = __builtin_amdgcn_mfma_f32_32x32x16_f16(zl[u], beh, accB, 0, 0, 0);
            accB = __builtin_amdgcn_mfma_f32_32x32x16_f16(zh[u], bel, accB, 0, 0, 0);
        }
        __builtin_amdgcn_s_setprio(0);

        // ---- epilogue: scores + running argmin (regs only) ----
        // C/D: col(code) = l&31, row = (g&3) + 8*(g>>2) + 4*(l>>5)
        const int c0 = kbase + kt * 32 + cid;
        #pragma unroll
        for (int g = 0; g < 16; ++g) {
            float d = fmaf(accB[g], 0.0009765625f, accA[g]);
            float s = fmaf(-2.0f, d, es);
            if (s < minv[g]) { minv[g] = s; mini[g] = c0; }
        }
        accA = (f32x16)0.0f; accB = (f32x16)0.0f;

        if (haveNext) __syncthreads();   // drains DMA (vmcnt) + swap
    }

    // ---- merge across 32 lanes per half (tie -> lower), write to ws ----
    #pragma unroll
    for (int g = 0; g < 16; ++g) {
        float v   = minv[g];
        int   idx = mini[g];
        #pragma unroll
        for (int m = 1; m < 32; m <<= 1) {
            float ov = __shfl_xor(v, m);
            int   oi = __shfl_xor(idx, m);
            if (ov < v || (ov == v && oi < idx)) { v = ov; idx = oi; }
        }
        const size_t row = wrow0 + (g & 3) + 8 * (g >> 2) + 4 * half;
        if (cid == 0) {
            wsv[(size_t)kh * N + row] = v;
            wsi[(size_t)kh * N + row] = idx;
        }
    }
}

// merge the 2 K-halves + gather embedding; 16 lanes per row, 16 rows/block
__global__ void merge_gather(const float* __restrict__ wsv, const int* __restrict__ wsi,
                             const float* __restrict__ cb, float* __restrict__ out) {
    const int t   = threadIdx.x;
    const int r   = blockIdx.x * 16 + (t >> 4);
    const int l16 = t & 15;
    const float v0 = wsv[r], v1 = wsv[N + r];
    const int   i0 = wsi[r], i1 = wsi[N + r];
    // half-0 indices < half-1 indices, so tie (v1==v0) -> i0 = lower index
    const int idx = (v1 < v0) ? i1 : i0;
    if (l16 == 0) out[(size_t)N * D + r] = (float)idx;
    const float4* src = reinterpret_cast<const float4*>(cb + (size_t)idx * D);
    float4*       dst = reinterpret_cast<float4*>(out + (size_t)r * D);
    #pragma unroll
    for (int it = 0; it < 4; ++it) dst[l16 + 16 * it] = src[l16 + 16 * it];
}

// ============================================================================
// Path B (fallback if ws too small): round-1 fp32 kernels (verified exact).
// ============================================================================
constexpr int BM = 128, BN = 128, TD = 32, ZS = 260, CS = 36;

__launch_bounds__(256)
__global__ void vq_kernel(const float* __restrict__ z, const float* __restrict__ cb,
                          const float* __restrict__ esq, float* __restrict__ out) {
    __shared__ float zs[BM * ZS];
    __shared__ float cs[BN * CS];
    const int tid = threadIdx.x;
    const int tx  = tid & 15;
    const int ty  = tid >> 4;
    const size_t row0 = (size_t)blockIdx.x * BM;
    #pragma unroll
    for (int i = 0; i < 32; ++i) {
        int f  = tid + i * 256;
        int r  = f >> 6;
        int c4 = (f & 63) * 4;
        *reinterpret_cast<float4*>(&zs[r * ZS + c4]) =
            *reinterpret_cast<const float4*>(z + (row0 + r) * D + c4);
    }
    float minv[8]; int mini[8];
    #pragma unroll
    for (int i = 0; i < 8; ++i) { minv[i] = 3.4e38f; mini[i] = 0; }
    for (int k0 = 0; k0 < K; k0 += BN) {
        float acc[8][8];
        #pragma unroll
        for (int i = 0; i < 8; ++i)
            #pragma unroll
            for (int j = 0; j < 8; ++j) acc[i][j] = 0.0f;
        for (int dc = 0; dc < D; dc += TD) {
            __syncthreads();
            int c = tid >> 3, c4 = (tid & 7) * 4;
            #pragma unroll
            for (int i = 0; i < 4; ++i)
                *reinterpret_cast<float4*>(&cs[(c + 32 * i) * CS + c4]) =
                    *reinterpret_cast<const float4*>(cb + (size_t)(k0 + c + 32 * i) * D + dc + c4);
            __syncthreads();
            for (int d4 = 0; d4 < TD; d4 += 4) {
                float4 a[8], b[8];
                #pragma unroll
                for (int i = 0; i < 8; ++i)
                    a[i] = *reinterpret_cast<const float4*>(&zs[(ty + 16 * i) * ZS + dc + d4]);
                #pragma unroll
                for (int j = 0; j < 8; ++j)
                    b[j] = *reinterpret_cast<const float4*>(&cs[(tx + 16 * j) * CS + d4]);
                #pragma unroll
                for (int i = 0; i < 8; ++i)
                    #pragma unroll
                    for (int j = 0; j < 8; ++j)
                        acc[i][j] += a[i].x * b[j].x + a[i].y * b[j].y
                                   + a[i].z * b[j].z + a[i].w * b[j].w;
            }
        }
        #pragma unroll
        for (int j = 0; j < 8; ++j) {
            int code = k0 + tx + 16 * j;
            float es = esq[code];
            #pragma unroll
            for (int i = 0; i < 8; ++i) {
                float score = fmaf(-2.0f, acc[i][j], es);
                if (score < minv[i]) { minv[i] = score; mini[i] = code; }
            }
        }
    }
    float* out_idx = out + (size_t)N * D;
    #pragma unroll
    for (int i = 0; i < 8; ++i) {
        float v = minv[i]; int idx = mini[i];
        #pragma unroll
        for (int m = 1; m < 16; m <<= 1) {
            float ov = __shfl_xor(v, m);
            int   oi = __shfl_xor(idx, m);
            if (ov < v || (ov == v && oi < idx)) { v = ov; idx = oi; }
        }
        size_t row = row0 + ty + 16 * i;
        if (tx == 0) out_idx[row] = (float)idx;
        const float4* src = reinterpret_cast<const float4*>(cb + (size_t)idx * D);
        float4*       dst = reinterpret_cast<float4*>(out + row * D);
        #pragma unroll
        for (int t = 0; t < 4; ++t) dst[tx + 16 * t] = src[tx + 16 * t];
    }
}

extern "C" void kernel_launch(void* const* d_in, const int* in_sizes, int n_in,
                              void* d_out, int out_size, void* d_ws, size_t ws_size,
                              hipStream_t stream) {
    const float* z   = (const float*)d_in[0];
    const float* cb  = (const float*)d_in[1];
    float*       out = (float*)d_out;

    const size_t cbt_bytes = (size_t)K * 512 * sizeof(f16);   // 8 MB
    const size_t esq_bytes = (size_t)K * sizeof(float);
    const size_t wsv_bytes = (size_t)2 * N * sizeof(float);
    const size_t wsi_bytes = (size_t)2 * N * sizeof(int);
    const size_t need = cbt_bytes + esq_bytes + wsv_bytes + wsi_bytes;

    if (ws_size >= need) {
        char* p = (char*)d_ws;
        f16*   cbt  = (f16*)p;                 p += cbt_bytes;
        float* esqp = (float*)p;               p += esq_bytes;
        float* wsv  = (float*)p;               p += wsv_bytes;
        int*   wsi  = (int*)p;
        esq_kernel<<<(K * 64) / 256, 256, 0, stream>>>(cb, esqp);
        cvt_t<<<(K * 64) / 256, 256, 0, stream>>>(cb, cbt);
        vq32<<<512, 256, 0, stream>>>(z, cbt, esqp, wsv, wsi);
        merge_gather<<<N / 16, 256, 0, stream>>>(wsv, wsi, cb, out);
    } else {
        float* esqp = (float*)d_ws;
        esq_kernel<<<(K * 64) / 256, 256, 0, stream>>>(cb, esqp);
        vq_kernel<<<N / BM, 256, 0, stream>>>(z, cb, esqp, out);
    }
}